// Round 13
// baseline (530.017 us; speedup 1.0000x reference)
//
#include <hip/hip_runtime.h>
#include <math.h>

static constexpr int F     = 64;
static constexpr int GRIDV = 64;
static constexpr int SEG   = 16 * GRIDV * GRIDV;   // 65536 clusters
static constexpr int G     = 256;                  // physical blocks (= #CUs, co-resident)
static constexpr int T     = 512;                  // threads per block
static constexpr int VB    = 512;                  // virtual blocks (2 per physical)
static constexpr int NBIN  = 512;                  // coarse bins (top 9 bits)
static constexpr int BSH   = 23;                   // key >> 23 -> coarse bin
static constexpr int NTBL  = NBIN * VB;            // 262144
static constexpr int ETBL  = NBIN * VB;            // 262144
static constexpr int JTBL  = NTBL + ETBL;          // 524288
static constexpr int SCAP  = 10240;                // subsort LDS staging cap (+27 sigma)
static constexpr int SMEMB = 57344;                // 56KB LDS union (subsort: 16K hist + 40K stage)

typedef float __attribute__((ext_vector_type(4))) f32x4;

__device__ __forceinline__ float wave_min(float v) {
    for (int o = 32; o > 0; o >>= 1) v = fminf(v, __shfl_down(v, o));
    return v;
}
__device__ __forceinline__ float wave_max(float v) {
    for (int o = 32; o > 0; o >>= 1) v = fmaxf(v, __shfl_down(v, o));
    return v;
}
__device__ __forceinline__ f32x4 vmax4(f32x4 a, f32x4 b) {
    f32x4 r;
    r.x = fmaxf(a.x, b.x); r.y = fmaxf(a.y, b.y);
    r.z = fmaxf(a.z, b.z); r.w = fmaxf(a.w, b.w);
    return r;
}

// Block-wide inclusive scan, shfl-based (2 barriers). EXEC-mask safe.
// Call-site discipline: a __syncthreads() must separate the RETURN (last wsum
// read) from the next call's first wsum write — verified at every site.
template <int NT>
__device__ __forceinline__ unsigned block_incl_scan(unsigned v, int t) {
    __shared__ unsigned wsum[NT / 64];
    int lane = t & 63, w = t >> 6;
    unsigned sc = v;
    #pragma unroll
    for (int o = 1; o < 64; o <<= 1) {
        unsigned u = __shfl_up(sc, o);
        if (lane >= o) sc += u;
    }
    if (lane == 63) wsum[w] = sc;
    __syncthreads();
    if (w == 0 && lane < NT / 64) {
        unsigned ws = wsum[lane];
        #pragma unroll
        for (int o = 1; o < NT / 64; o <<= 1) {
            unsigned u = __shfl_up(ws, o);
            if (lane >= o) ws += u;
        }
        wsum[lane] = ws;
    }
    __syncthreads();
    return sc + ((w > 0) ? wsum[w - 1] : 0u);
}

// Device-scope grid barrier. Safe because grid == #CUs and resources give
// >=1 resident block/CU (512 thr, <=56.2KB LDS, <=256 VGPR) -> all co-resident.
__device__ __forceinline__ void gbar(unsigned* bar, unsigned gen) {
    __syncthreads();
    if (threadIdx.x == 0) {
        __threadfence();                      // release prior writes (device scope)
        atomicAdd(bar, 1u);
        unsigned target = gen * (unsigned)G;
        while (__hip_atomic_load(bar, __ATOMIC_RELAXED, __HIP_MEMORY_SCOPE_AGENT) < target)
            __builtin_amdgcn_s_sleep(2);
        __threadfence();                      // acquire side
    }
    __syncthreads();
}

__global__ void k_binit(unsigned* bar) { *bar = 0u; }

struct Args {
    const float2* pos; const int* batch; const float* x; const int* ei;
    int n, e;
    unsigned* bar;
    float2* pmin; unsigned* blksum;
    int* cl; unsigned* table; unsigned* keysA; unsigned* keysB;
    unsigned* pc; unsigned* pn; float2* ppos;
    unsigned* node_off; int* node_sorted; float* pmax;
    float* out_x; float2* out_pos;
    float* out_erow; float* out_ecol; float* out_val; float2* out_attr;
};

__global__ __launch_bounds__(T, 2) void k_mega(Args a) {
    __shared__ __align__(16) unsigned char SM[SMEMB];
    __shared__ float s_red[16];
    __shared__ unsigned s_tot;
    const int b = blockIdx.x, t = threadIdx.x;
    const int lane = t & 63, wid = t >> 6;
    const int n = a.n, e = a.e;

    // ===== P1: per-block partial min of pos =====
    {
        float mx = INFINITY, my = INFINITY;
        for (int k = 0; k < 8; ++k) {
            int i = b * T + t + k * G * T;
            if (i < n) { float2 p = a.pos[i]; mx = fminf(mx, p.x); my = fminf(my, p.y); }
        }
        mx = wave_min(mx); my = wave_min(my);
        if (lane == 0) { s_red[wid] = mx; s_red[8 + wid] = my; }
        __syncthreads();
        if (t == 0) {
            for (int i = 1; i < 8; ++i) { mx = fminf(mx, s_red[i]); my = fminf(my, s_red[8 + i]); }
            a.pmin[b] = make_float2(mx, my);
        }
    }
    gbar(a.bar, 1);

    // ===== P2: global min (redundant per block) + cluster ids + node hist =====
    {
        float mxv = INFINITY, myv = INFINITY;
        if (t < G) { float2 pp = a.pmin[t]; mxv = pp.x; myv = pp.y; }
        mxv = wave_min(mxv); myv = wave_min(myv);
        if (lane == 0) { s_red[wid] = mxv; s_red[8 + wid] = myv; }
        __syncthreads();
        float sx = s_red[0], sy = s_red[8];
        #pragma unroll
        for (int i = 1; i < 8; ++i) { sx = fminf(sx, s_red[i]); sy = fminf(sy, s_red[8 + i]); }
        __syncthreads();
        unsigned* hist = (unsigned*)SM;              // [NBIN]
        for (int v = 0; v < 2; ++v) {
            int vb = 2 * b + v;
            hist[t] = 0u;
            __syncthreads();
            for (int k = 0; k < 4; ++k) {
                int i = vb * T + t + k * VB * T;
                if (i < n) {
                    float2 p = a.pos[i];
                    int vx = min(max((int)floorf((p.x - sx) * 64.0f), 0), GRIDV - 1);
                    int vy = min(max((int)floorf((p.y - sy) * 64.0f), 0), GRIDV - 1);
                    int c = a.batch[i] * (GRIDV * GRIDV) + vy * GRIDV + vx;
                    a.cl[i] = c;
                    atomicAdd(&hist[(unsigned)c >> 7], 1u);
                }
            }
            __syncthreads();
            a.table[t * VB + vb] = hist[t];
            __syncthreads();
        }
    }
    gbar(a.bar, 2);

    // ===== P3: edge keys + edge coarse histogram =====
    {
        unsigned* hist = (unsigned*)SM;
        for (int v = 0; v < 2; ++v) {
            int vb = 2 * b + v;
            hist[t] = 0u;
            __syncthreads();
            for (int k = 0; k < 16; ++k) {
                int i = vb * T + t + k * VB * T;
                if (i < e) {
                    unsigned r = (unsigned)a.cl[a.ei[i]];
                    unsigned c = (unsigned)a.cl[a.ei[e + i]];
                    unsigned kk = (r << 16) | c;
                    a.keysA[i] = kk;
                    atomicAdd(&hist[kk >> BSH], 1u);
                }
            }
            __syncthreads();
            a.table[NTBL + t * VB + vb] = hist[t];
            __syncthreads();
        }
    }
    gbar(a.bar, 3);

    // ===== P4: joint scan stage 1 (two 1024-entry chunks per block) =====
    {
        for (int v = 0; v < 2; ++v) {
            int c = 2 * b + v;
            int base = c * 1024;
            unsigned v0 = a.table[base + t];
            unsigned v1 = a.table[base + 512 + t];
            unsigned i0 = block_incl_scan<T>(v0, t);
            if (t == 511) s_tot = i0;
            __syncthreads();
            unsigned t0 = s_tot;
            unsigned i1 = block_incl_scan<T>(v1, t) + t0;
            a.table[base + t]       = i0 - v0;
            a.table[base + 512 + t] = i1 - v1;
            if (t == 511) a.blksum[c] = i1;
            __syncthreads();
        }
    }
    gbar(a.bar, 4);

    // ===== P5: scan stage 2 (add chunk bases) =====
    {
        unsigned* sh = (unsigned*)SM;   // [512]
        for (int v = 0; v < 2; ++v) {
            int c = 2 * b + v;
            int base = c * 1024;
            sh[t] = (t < c) ? a.blksum[t] : 0u;
            __syncthreads();
            for (int s = 256; s > 0; s >>= 1) {
                if (t < s) sh[t] += sh[t + s];
                __syncthreads();
            }
            unsigned add = sh[0];
            a.table[base + t]       += add;
            a.table[base + 512 + t] += add;
            __syncthreads();
        }
        if (b == 0 && t == 0) a.table[JTBL] = (unsigned)(n + e);
    }
    gbar(a.bar, 5);

    // ===== P6: node coarse partition (counts from scanned diffs) =====
    {
        unsigned* stage_c  = (unsigned*)SM;                 // 2048
        unsigned* stage_n  = stage_c + 2048;                // 2048
        float*    stage_px = (float*)(stage_n + 2048);      // 2048
        float*    stage_py = stage_px + 2048;               // 2048
        unsigned* h    = (unsigned*)(stage_py + 2048);      // 512
        unsigned* cur  = h + 512;                           // 512
        unsigned* tbl  = cur + 512;                         // 512
        for (int v = 0; v < 2; ++v) {
            int vb = 2 * b + v;
            unsigned aof = a.table[t * VB + vb];            // boundary table[NTBL] = n
            unsigned hv  = a.table[t * VB + vb + 1] - aof;
            tbl[t] = aof; h[t] = hv;
            unsigned incl = block_incl_scan<T>(hv, t);
            cur[t] = incl - hv;
            __syncthreads();
            for (int k = 0; k < 4; ++k) {
                int i = vb * T + t + k * VB * T;
                if (i < n) {
                    unsigned c = (unsigned)a.cl[i];
                    float2 p = a.pos[i];
                    unsigned q = atomicAdd(&cur[c >> 7], 1u);
                    stage_c[q] = c; stage_n[q] = (unsigned)i;
                    stage_px[q] = p.x; stage_py[q] = p.y;
                }
            }
            __syncthreads();
            int cnt = (int)cur[NBIN - 1];
            for (int j = t; j < cnt; j += T) {
                unsigned c = stage_c[j];
                unsigned bin = c >> 7;
                unsigned start = cur[bin] - h[bin];
                unsigned g2 = tbl[bin] + ((unsigned)j - start);
                a.pc[g2] = c; a.pn[g2] = stage_n[j];
                a.ppos[g2] = make_float2(stage_px[j], stage_py[j]);
            }
            __syncthreads();
        }
    }
    gbar(a.bar, 6);

    // ===== P7a: ngroup per vb: node_off, pos means, grouped node order =====
    {
        unsigned* cnt = (unsigned*)SM;       // 128
        unsigned* sc  = cnt + 128;
        unsigned* cur = sc + 128;
        float* psx = (float*)(cur + 128);
        float* psy = psx + 128;
        for (int v = 0; v < 2; ++v) {
            int vb = 2 * b + v;
            if (t < 128) { cnt[t] = 0u; psx[t] = 0.f; psy[t] = 0.f; }
            __syncthreads();
            int beg = (int)a.table[vb * VB];
            int end = (int)a.table[(vb + 1) * VB];
            for (int i = beg + t; i < end; i += T) {
                unsigned c = a.pc[i] & 127u;
                float2 p = a.ppos[i];
                atomicAdd(&cnt[c], 1u);
                atomicAdd(&psx[c], p.x);
                atomicAdd(&psy[c], p.y);
            }
            __syncthreads();
            if (t < 128) sc[t] = cnt[t];
            __syncthreads();
            for (int s = 1; s < 128; s <<= 1) {
                unsigned u = (t >= s && t < 128) ? sc[t - s] : 0u;
                __syncthreads();
                if (t < 128) sc[t] += u;
                __syncthreads();
            }
            if (t < 128) {
                unsigned basec = (unsigned)beg + sc[t] - cnt[t];
                a.node_off[vb * 128 + t] = basec;
                cur[t] = basec;
                unsigned c2 = cnt[t];
                a.out_pos[vb * 128 + t] = c2 ? make_float2(psx[t] / (float)c2, psy[t] / (float)c2)
                                             : make_float2(0.f, 0.f);
            }
            if (vb == VB - 1 && t == 0) a.node_off[SEG] = (unsigned)n;
            __syncthreads();
            for (int i = beg + t; i < end; i += T) {
                unsigned c = a.pc[i] & 127u;
                unsigned slot = atomicAdd(&cur[c], 1u);
                a.node_sorted[slot] = (int)a.pn[i];
            }
            __syncthreads();
        }
    }
    // ===== P7b: edge coarse partition (keysA -> keysB) =====
    {
        unsigned* stg  = (unsigned*)SM;          // 8192
        unsigned* h    = stg + 8192;             // 512
        unsigned* cur  = h + 512;                // 512
        unsigned* tbl2 = cur + 512;              // 512
        for (int v = 0; v < 2; ++v) {
            int vb = 2 * b + v;
            unsigned aof = a.table[NTBL + t * VB + vb] - (unsigned)n;     // boundary = n+e
            unsigned hv  = (a.table[NTBL + t * VB + vb + 1] - (unsigned)n) - aof;
            tbl2[t] = aof; h[t] = hv;
            unsigned incl = block_incl_scan<T>(hv, t);
            cur[t] = incl - hv;
            __syncthreads();
            for (int k = 0; k < 16; ++k) {
                int i = vb * T + t + k * VB * T;
                if (i < e) {
                    unsigned kk = a.keysA[i];
                    unsigned p = atomicAdd(&cur[kk >> BSH], 1u);
                    stg[p] = kk;
                }
            }
            __syncthreads();
            int cnt2 = (int)cur[NBIN - 1];
            for (int j = t; j < cnt2; j += T) {
                unsigned kk = stg[j];
                unsigned bin = kk >> BSH;
                unsigned start = cur[bin] - h[bin];
                a.keysB[tbl2[bin] + ((unsigned)j - start)] = kk;
            }
            __syncthreads();
        }
    }
    gbar(a.bar, 7);

    // ===== P8a: subsort per vb (12-bit LDS counting sort + run-finish) + pmax =====
    {
        unsigned* hist = (unsigned*)SM;              // 4096 (16KB)
        unsigned* stg  = (unsigned*)SM + 4096;       // SCAP (40KB)
        for (int v = 0; v < 2; ++v) {
            int vb = 2 * b + v;
            int beg = (int)(a.table[NTBL + vb * VB] - (unsigned)n);
            int end = (int)(a.table[NTBL + (vb + 1) * VB] - (unsigned)n);
            int len = end - beg;
            float am = 0.f;
            if (len > 0) {
                for (int j = t; j < 4096; j += T) hist[j] = 0u;
                __syncthreads();
                for (int i = beg + t; i < end; i += T) {
                    unsigned d = (a.keysB[i] >> 11) & 4095u;
                    atomicAdd(&hist[((d & 7u) << 9) | (d >> 3)], 1u);    // slot: d = t*8+u order
                }
                __syncthreads();
                unsigned loc[8];
                unsigned s = 0;
                #pragma unroll
                for (int u = 0; u < 8; ++u) { loc[u] = s; s += hist[u * 512 + t]; }
                unsigned incl = block_incl_scan<T>(s, t);
                bool inlds = (len <= SCAP);
                unsigned base0 = (inlds ? 0u : (unsigned)beg) + incl - s;
                #pragma unroll
                for (int u = 0; u < 8; ++u) hist[u * 512 + t] = base0 + loc[u];
                __syncthreads();
                if (inlds) {
                    for (int i = beg + t; i < end; i += T) {
                        unsigned k = a.keysB[i];
                        unsigned d = (k >> 11) & 4095u;
                        stg[atomicAdd(&hist[((d & 7u) << 9) | (d >> 3)], 1u)] = k;
                    }
                    __syncthreads();
                    for (int j = t; j < len; j += T) {   // run-finish: equal key>>11 groups
                        unsigned hi = stg[j] >> 11;
                        if (j > 0 && (stg[j - 1] >> 11) == hi) continue;
                        int rend = j + 1;
                        while (rend < len && (stg[rend] >> 11) == hi) ++rend;
                        for (int a2 = j + 1; a2 < rend; ++a2) {
                            unsigned vv = stg[a2]; int c = a2 - 1;
                            while (c >= j && stg[c] > vv) { stg[c + 1] = stg[c]; --c; }
                            stg[c + 1] = vv;
                        }
                    }
                    __syncthreads();
                    for (int j = t; j < len; j += T) {
                        unsigned k = stg[j];
                        a.keysA[beg + j] = k;
                        bool first = (j == 0) || (stg[j - 1] != k);
                        unsigned r = k >> 16, c = k & 0xFFFFu;
                        if (first && r != c) {
                            float2 pr = a.out_pos[r], pcc = a.out_pos[c];
                            am = fmaxf(am, fmaxf(fabsf(pr.x - pcc.x), fabsf(pr.y - pcc.y)));
                        }
                    }
                } else {
                    // 27-sigma-unreachable fallback in global memory
                    for (int i = beg + t; i < end; i += T) {
                        unsigned k = a.keysB[i];
                        unsigned d = (k >> 11) & 4095u;
                        a.keysA[atomicAdd(&hist[((d & 7u) << 9) | (d >> 3)], 1u)] = k;
                    }
                    __threadfence();
                    __syncthreads();
                    for (int j = beg + t; j < end; j += T) {
                        unsigned hi = a.keysA[j] >> 11;
                        if (j > beg && (a.keysA[j - 1] >> 11) == hi) continue;
                        int rend = j + 1;
                        while (rend < end && (a.keysA[rend] >> 11) == hi) ++rend;
                        for (int a2 = j + 1; a2 < rend; ++a2) {
                            unsigned vv = a.keysA[a2]; int c = a2 - 1;
                            while (c >= j && a.keysA[c] > vv) { a.keysA[c + 1] = a.keysA[c]; --c; }
                            a.keysA[c + 1] = vv;
                        }
                    }
                    __threadfence();
                    __syncthreads();
                    for (int j = beg + t; j < end; j += T) {
                        unsigned k = a.keysA[j];
                        bool first = (j == beg) || (a.keysA[j - 1] != k);
                        unsigned r = k >> 16, c = k & 0xFFFFu;
                        if (first && r != c) {
                            float2 pr = a.out_pos[r], pcc = a.out_pos[c];
                            am = fmaxf(am, fmaxf(fabsf(pr.x - pcc.x), fabsf(pr.y - pcc.y)));
                        }
                    }
                }
            }
            __syncthreads();
            am = wave_max(am);
            if (lane == 0) s_red[wid] = am;
            __syncthreads();
            if (t == 0) {
                float m = s_red[0];
                #pragma unroll
                for (int i = 1; i < 8; ++i) m = fmaxf(m, s_red[i]);
                a.pmax[vb] = m;
            }
            __syncthreads();
        }
    }
    // ===== P8b: feature-max pool (same-block node data; no LDS) =====
    {
        for (int v = 0; v < 2; ++v) {
            int vb = 2 * b + v;
            for (int k2 = 0; k2 < 16; ++k2) {
                int s = vb * 128 + wid + 8 * k2;
                unsigned pbeg = a.node_off[s], pend = a.node_off[s + 1];
                int g2  = lane >> 4;
                int cl4 = (lane & 15) << 2;
                f32x4 m0, m1, m2, m3;
                m0.x = m0.y = m0.z = m0.w = -INFINITY;
                m1 = m0; m2 = m0; m3 = m0;
                for (unsigned base2 = pbeg; base2 < pend; base2 += 64) {
                    int m = (int)min(64u, pend - base2);
                    int nd_my = (lane < m) ? a.node_sorted[base2 + lane] : 0;
                    int last = m - 1;
                    int K = (m + 15) >> 4;           // wave-uniform trips, clamped rows
                    for (int k = 0; k < K; ++k) {
                        int j = g2 + (k << 4);
                        int j0 = min(j, last);
                        int j1 = min(j + 4, last);
                        int j2 = min(j + 8, last);
                        int j3 = min(j + 12, last);
                        int n0 = __shfl(nd_my, j0);
                        int n1 = __shfl(nd_my, j1);
                        int n2 = __shfl(nd_my, j2);
                        int n3 = __shfl(nd_my, j3);
                        f32x4 v0 = __builtin_nontemporal_load((const f32x4*)&a.x[(size_t)n0 * F + cl4]);
                        f32x4 v1 = __builtin_nontemporal_load((const f32x4*)&a.x[(size_t)n1 * F + cl4]);
                        f32x4 v2 = __builtin_nontemporal_load((const f32x4*)&a.x[(size_t)n2 * F + cl4]);
                        f32x4 v3 = __builtin_nontemporal_load((const f32x4*)&a.x[(size_t)n3 * F + cl4]);
                        m0 = vmax4(m0, v0);
                        m1 = vmax4(m1, v1);
                        m2 = vmax4(m2, v2);
                        m3 = vmax4(m3, v3);
                    }
                }
                m0 = vmax4(vmax4(m0, m1), vmax4(m2, m3));
                #pragma unroll
                for (int o = 16; o <= 32; o <<= 1) {
                    m0.x = fmaxf(m0.x, __shfl_xor(m0.x, o));
                    m0.y = fmaxf(m0.y, __shfl_xor(m0.y, o));
                    m0.z = fmaxf(m0.z, __shfl_xor(m0.z, o));
                    m0.w = fmaxf(m0.w, __shfl_xor(m0.w, o));
                }
                if (g2 == 0) {
                    f32x4 r;
                    if (pend > pbeg) r = m0;
                    else { r.x = r.y = r.z = r.w = 0.f; }
                    *(f32x4*)&a.out_x[(size_t)s * F + cl4] = r;
                }
            }
        }
    }
    gbar(a.bar, 8);

    // ===== P9: final edge outputs =====
    {
        float m = a.pmax[t];          // t < 512 == NBIN
        m = wave_max(m);
        if (lane == 0) s_red[wid] = m;
        __syncthreads();
        float dm = s_red[0];
        #pragma unroll
        for (int i = 1; i < 8; ++i) dm = fmaxf(dm, s_red[i]);
        float denom = 2.0f * dm;
        for (int k2 = 0; k2 < 32; ++k2) {
            int i = b * T + t + k2 * G * T;
            if (i < e) {
                unsigned kk = a.keysA[i];
                bool first = (i == 0) || (a.keysA[i - 1] != kk);
                unsigned r = kk >> 16, c = kk & 0xFFFFu;
                bool valid = first && (r != c);
                float ax = 0.f, ay = 0.f;
                if (valid) {
                    float2 pr = a.out_pos[r], pcc = a.out_pos[c];
                    ax = (pr.x - pcc.x) / denom + 0.5f;
                    ay = (pr.y - pcc.y) / denom + 0.5f;
                }
                a.out_erow[i] = valid ? (float)r : 0.f;
                a.out_ecol[i] = valid ? (float)c : 0.f;
                a.out_val[i]  = valid ? 1.f : 0.f;
                a.out_attr[i] = make_float2(ax, ay);
            }
        }
    }
}

extern "C" void kernel_launch(void* const* d_in, const int* in_sizes, int n_in,
                              void* d_out, int out_size, void* d_ws, size_t ws_size,
                              hipStream_t stream) {
    const float* x    = (const float*)d_in[0];
    const float* pos  = (const float*)d_in[1];
    const int* batch  = (const int*)d_in[2];
    const int* ei     = (const int*)d_in[3];
    const int n = in_sizes[2];
    const int e = in_sizes[3] / 2;

    float* out      = (float*)d_out;
    float* out_x    = out;                                   // [SEG, F]
    float* out_pos  = out_x  + (size_t)SEG * F;              // [SEG, 2]
    float* out_erow = out_pos + (size_t)SEG * 2;             // [E]
    float* out_ecol = out_erow + e;                          // [E]
    float* out_attr = out_ecol + e;                          // [E, 2]
    float* out_val  = out_attr + (size_t)2 * e;              // [E]

    // Workspace layout — no aliasing between any two live ranges.
    char* w = (char*)d_ws;
    unsigned* bar         = (unsigned*)w;                            // 1 u32 (pad 256)
    int*      cl          = (int*)(w + 256);                         // [n]
    int*      node_sorted = (int*)(w + 256 + (size_t)n * 4);         // [n]
    unsigned* node_off    = (unsigned*)(w + 256 + (size_t)n * 8);    // [SEG+1]
    unsigned* table       = node_off + SEG + 1;                      // [JTBL+1]
    unsigned* keysA       = table + JTBL + 1;                        // [e]
    unsigned* keysB       = keysA + e;                               // [e]
    unsigned* pc          = keysB + e;                               // [n]
    unsigned* pn          = pc + n;                                  // [n]
    float2*   ppos        = (float2*)(pn + n);                       // [n]
    float2*   pmin        = (float2*)(ppos + n);                     // [G]
    unsigned* blksum      = (unsigned*)(pmin + G);                   // [VB]
    float*    pmax        = (float*)(blksum + VB);                   // [NBIN]

    Args args;
    args.pos = (const float2*)pos; args.batch = batch; args.x = x; args.ei = ei;
    args.n = n; args.e = e;
    args.bar = bar;
    args.pmin = pmin; args.blksum = blksum;
    args.cl = cl; args.table = table; args.keysA = keysA; args.keysB = keysB;
    args.pc = pc; args.pn = pn; args.ppos = ppos;
    args.node_off = node_off; args.node_sorted = node_sorted; args.pmax = pmax;
    args.out_x = out_x; args.out_pos = (float2*)out_pos;
    args.out_erow = out_erow; args.out_ecol = out_ecol; args.out_val = out_val;
    args.out_attr = (float2*)out_attr;

    k_binit<<<1, 1, 0, stream>>>(bar);
    k_mega<<<G, T, 0, stream>>>(args);
}

// Round 14
// 248.359 us; speedup vs baseline: 2.1341x; 2.1341x over previous
//
#include <hip/hip_runtime.h>
#include <math.h>

static constexpr int F     = 64;
static constexpr int GRIDV = 64;
static constexpr int SEG   = 16 * GRIDV * GRIDV;   // 65536 clusters
static constexpr int MINB  = 256;                  // blocks for k_min
// edge pipeline
static constexpr int GPART = 512;                  // blocks for edge hist/partition
static constexpr int PTHR  = 512;                  // threads for edge hist/partition
static constexpr int NBIN  = 512;                  // coarse bins (top 9 bits)
static constexpr int BSH   = 23;                   // key >> 23 -> coarse bin
static constexpr int ETBL  = NBIN * GPART;         // 262144
static constexpr int SCAP  = 10240;                // subsort LDS staging cap (+27 sigma)
// node pipeline
static constexpr int NGP   = 512;                  // blocks for node partition
static constexpr int NTH   = 256;                  // threads for node partition
static constexpr int NTBL  = NBIN * NGP;           // 262144

typedef float __attribute__((ext_vector_type(4))) f32x4;

__device__ __forceinline__ float wave_min(float v) {
    for (int o = 32; o > 0; o >>= 1) v = fminf(v, __shfl_down(v, o));
    return v;
}
__device__ __forceinline__ float wave_max(float v) {
    for (int o = 32; o > 0; o >>= 1) v = fmaxf(v, __shfl_down(v, o));
    return v;
}
__device__ __forceinline__ f32x4 vmax4(f32x4 a, f32x4 b) {
    f32x4 r;
    r.x = fmaxf(a.x, b.x); r.y = fmaxf(a.y, b.y);
    r.z = fmaxf(a.z, b.z); r.w = fmaxf(a.w, b.w);
    return r;
}

// Block-wide inclusive scan, shfl-based (2 barriers). EXEC-mask safe.
template <int NT>
__device__ __forceinline__ unsigned block_incl_scan(unsigned v, int t) {
    __shared__ unsigned wsum[NT / 64];
    int lane = t & 63, w = t >> 6;
    unsigned sc = v;
    #pragma unroll
    for (int o = 1; o < 64; o <<= 1) {
        unsigned u = __shfl_up(sc, o);
        if (lane >= o) sc += u;
    }
    if (lane == 63) wsum[w] = sc;
    __syncthreads();
    if (w == 0 && lane < NT / 64) {
        unsigned ws = wsum[lane];
        #pragma unroll
        for (int o = 1; o < NT / 64; o <<= 1) {
            unsigned u = __shfl_up(ws, o);
            if (lane >= o) ws += u;
        }
        wsum[lane] = ws;
    }
    __syncthreads();
    return sc + ((w > 0) ? wsum[w - 1] : 0u);
}

// ---- per-block partial min of pos ----
__global__ void k_min(const float2* __restrict__ pos, int n, float2* __restrict__ pmin) {
    __shared__ float shx[4], shy[4];
    int stride = gridDim.x * blockDim.x;
    float mx = INFINITY, my = INFINITY;
    for (int i = blockIdx.x * blockDim.x + threadIdx.x; i < n; i += stride) {
        float2 p = pos[i];
        mx = fminf(mx, p.x); my = fminf(my, p.y);
    }
    mx = wave_min(mx); my = wave_min(my);
    int w = threadIdx.x >> 6;
    if ((threadIdx.x & 63) == 0) { shx[w] = mx; shy[w] = my; }
    __syncthreads();
    if (threadIdx.x == 0) {
        mx = fminf(fminf(shx[0], shx[1]), fminf(shx[2], shx[3]));
        my = fminf(fminf(shy[0], shy[1]), fminf(shy[2], shy[3]));
        pmin[blockIdx.x] = make_float2(mx, my);
    }
}

__global__ void k_minred(const float2* __restrict__ pmin, int nb, unsigned* hdr) {
    __shared__ float shx[4], shy[4];
    int t = threadIdx.x;
    float mx = INFINITY, my = INFINITY;
    for (int i = t; i < nb; i += blockDim.x) {
        float2 p = pmin[i];
        mx = fminf(mx, p.x); my = fminf(my, p.y);
    }
    mx = wave_min(mx); my = wave_min(my);
    int w = t >> 6;
    if ((t & 63) == 0) { shx[w] = mx; shy[w] = my; }
    __syncthreads();
    if (t == 0) {
        int nw = (int)(blockDim.x + 63) >> 6;
        for (int i = 1; i < nw; ++i) { mx = fminf(mx, shx[i]); my = fminf(my, shy[i]); }
        hdr[0] = (unsigned)__float_as_int(mx);
        hdr[1] = (unsigned)__float_as_int(my);
    }
}

// ---- cluster ids + coarse 512-bin per-block table (no global atomics) ----
__global__ __launch_bounds__(NTH) void k_cluster(const float2* __restrict__ pos,
                          const int* __restrict__ batch, int n,
                          const unsigned* __restrict__ hdr, int* __restrict__ cl,
                          unsigned* __restrict__ ntable) {
    __shared__ unsigned hist[NBIN];
    int t = threadIdx.x, b = blockIdx.x;
    for (int j = t; j < NBIN; j += NTH) hist[j] = 0u;
    __syncthreads();
    float sx = __int_as_float((int)hdr[0]);
    float sy = __int_as_float((int)hdr[1]);
    for (int i = b * NTH + t; i < n; i += NGP * NTH) {
        float2 p = pos[i];
        int vx = min(max((int)floorf((p.x - sx) * 64.0f), 0), GRIDV - 1);
        int vy = min(max((int)floorf((p.y - sy) * 64.0f), 0), GRIDV - 1);
        int c = batch[i] * (GRIDV * GRIDV) + vy * GRIDV + vx;
        cl[i] = c;
        atomicAdd(&hist[(unsigned)c >> 7], 1u);
    }
    __syncthreads();
    for (int j = t; j < NBIN; j += NTH) ntable[j * NGP + b] = hist[j];
}

// ---- hierarchical exclusive scan: stage 1 (shfl-based, 2 barriers) ----
__global__ void k_scan1(const unsigned* __restrict__ cnt, unsigned* __restrict__ off,
                        unsigned* __restrict__ blksum) {
    int t = threadIdx.x;
    int g = blockIdx.x * 1024 + t;
    unsigned v = cnt[g];
    unsigned incl = block_incl_scan<1024>(v, t);
    off[g] = incl - v;
    if (t == 1023) blksum[blockIdx.x] = incl;
}

// stage 2: add block bases; up to 256 stage-1 blocks
__global__ void k_scan_add(unsigned* __restrict__ off, const unsigned* __restrict__ blksum,
                           int nblk, int n, unsigned total) {
    __shared__ unsigned sh[256];
    int t = threadIdx.x, b = blockIdx.x;
    if (t < 256) sh[t] = (t < b && t < nblk) ? blksum[t] : 0u;
    __syncthreads();
    for (int s = 128; s > 0; s >>= 1) {
        if (t < s) sh[t] += sh[t + s];
        __syncthreads();
    }
    off[b * 1024 + t] += sh[0];
    if (b == 0 && t == 0) off[n] = total;
}

// ---- node coarse partition; per-block counts from SCANNED-TABLE DIFFS ----
__global__ __launch_bounds__(NTH) void k_npart(const int* __restrict__ cl,
                       const float2* __restrict__ pos, int n,
                       const unsigned* __restrict__ ntable,
                       unsigned* __restrict__ pc, unsigned* __restrict__ pn,
                       float2* __restrict__ ppos) {
    __shared__ unsigned stage_c[2048], stage_n[2048];
    __shared__ float stage_px[2048], stage_py[2048];
    __shared__ unsigned h[NBIN], cur[NBIN], tbl_s[NBIN];
    int t = threadIdx.x, b = blockIdx.x;
    for (int j = t; j < NBIN; j += NTH) {
        unsigned a = ntable[j * NGP + b];       // boundary ntable[NTBL] = n
        tbl_s[j] = a;
        h[j] = ntable[j * NGP + b + 1] - a;
    }
    __syncthreads();
    unsigned a0 = h[2 * t], a1 = h[2 * t + 1];
    unsigned incl = block_incl_scan<NTH>(a0 + a1, t);
    unsigned base = incl - (a0 + a1);
    cur[2 * t] = base;
    cur[2 * t + 1] = base + a0;
    __syncthreads();
    for (int i = b * NTH + t; i < n; i += NGP * NTH) {
        unsigned c = (unsigned)cl[i];
        float2 p = pos[i];
        unsigned q = atomicAdd(&cur[c >> 7], 1u);
        stage_c[q] = c; stage_n[q] = (unsigned)i;
        stage_px[q] = p.x; stage_py[q] = p.y;
    }
    __syncthreads();
    int cnt = (int)cur[NBIN - 1];          // = block total after placement
    for (int j = t; j < cnt; j += NTH) {
        unsigned c = stage_c[j];
        unsigned bin = c >> 7;
        unsigned start = cur[bin] - h[bin];
        unsigned g = tbl_s[bin] + ((unsigned)j - start);
        pc[g] = c; pn[g] = stage_n[j];
        ppos[g] = make_float2(stage_px[j], stage_py[j]);
    }
}

// ---- per coarse bin: derive node_off, pos means, grouped node order ----
__global__ __launch_bounds__(256) void k_ngroup(const unsigned* __restrict__ pc,
                         const unsigned* __restrict__ pn, const float2* __restrict__ ppos,
                         const unsigned* __restrict__ ntable, int n,
                         unsigned* __restrict__ node_off, int* __restrict__ node_sorted,
                         float2* __restrict__ out_pos) {
    __shared__ unsigned cnt[128], sc[128], cur[128];
    __shared__ float psx[128], psy[128];
    int b = blockIdx.x, t = threadIdx.x;
    if (t < 128) { cnt[t] = 0u; psx[t] = 0.f; psy[t] = 0.f; }
    __syncthreads();
    int beg = (int)ntable[b * NGP];
    int end = (int)ntable[(b + 1) * NGP];
    for (int i = beg + t; i < end; i += 256) {
        unsigned c = pc[i] & 127u;
        float2 p = ppos[i];
        atomicAdd(&cnt[c], 1u);
        atomicAdd(&psx[c], p.x);
        atomicAdd(&psy[c], p.y);
    }
    __syncthreads();
    if (t < 128) sc[t] = cnt[t];
    __syncthreads();
    for (int s = 1; s < 128; s <<= 1) {
        unsigned u = (t >= s && t < 128) ? sc[t - s] : 0u;
        __syncthreads();
        if (t < 128) sc[t] += u;
        __syncthreads();
    }
    if (t < 128) {
        unsigned basec = (unsigned)beg + sc[t] - cnt[t];
        node_off[b * 128 + t] = basec;
        cur[t] = basec;
        unsigned c2 = cnt[t];
        out_pos[b * 128 + t] = c2 ? make_float2(psx[t] / (float)c2, psy[t] / (float)c2)
                                  : make_float2(0.f, 0.f);
    }
    if (b == NBIN - 1 && t == 0) node_off[SEG] = (unsigned)n;
    __syncthreads();
    for (int i = beg + t; i < end; i += 256) {
        unsigned c = pc[i] & 127u;
        unsigned slot = atomicAdd(&cur[c], 1u);
        node_sorted[slot] = (int)pn[i];
    }
}

// ---- feature max: wave-coalesced node-id load + shfl broadcast, 8-deep MLP ----
// Row loop: WAVE-UNIFORM trip count with CLAMPED row indices (idempotent for
// max). Divergent trips would make __shfl read EXEC=0 lanes -> 0 on CDNA.
__global__ __launch_bounds__(256) void k_pool(const float* __restrict__ x,
                      const int* __restrict__ node_sorted, const unsigned* __restrict__ off,
                      float* __restrict__ out_x) {
    int wid  = threadIdx.x >> 6;
    int lane = threadIdx.x & 63;
    int s = blockIdx.x * 4 + wid;
    unsigned beg = off[s], end = off[s + 1];
    int g   = lane >> 4;            // row offset 0..3
    int cl4 = (lane & 15) << 2;     // column base
    f32x4 m0, m1, m2, m3, m4, m5, m6, m7;
    m0.x = m0.y = m0.z = m0.w = -INFINITY;
    m1 = m0; m2 = m0; m3 = m0; m4 = m0; m5 = m0; m6 = m0; m7 = m0;
    for (unsigned base = beg; base < end; base += 64) {
        int m = (int)min(64u, end - base);
        int nd_my = (lane < m) ? node_sorted[base + lane] : 0;
        int last = m - 1;
        int K = (m + 31) >> 5;                    // uniform across the wave
        for (int k = 0; k < K; ++k) {
            int j = g + (k << 5);
            int j0 = min(j, last);                // clamped -> duplicates are
            int j1 = min(j + 4, last);            // idempotent under max
            int j2 = min(j + 8, last);
            int j3 = min(j + 12, last);
            int j4 = min(j + 16, last);
            int j5 = min(j + 20, last);
            int j6 = min(j + 24, last);
            int j7 = min(j + 28, last);
            int n0 = __shfl(nd_my, j0);
            int n1 = __shfl(nd_my, j1);
            int n2 = __shfl(nd_my, j2);
            int n3 = __shfl(nd_my, j3);
            int n4 = __shfl(nd_my, j4);
            int n5 = __shfl(nd_my, j5);
            int n6 = __shfl(nd_my, j6);
            int n7 = __shfl(nd_my, j7);
            f32x4 v0 = __builtin_nontemporal_load((const f32x4*)&x[(size_t)n0 * F + cl4]);
            f32x4 v1 = __builtin_nontemporal_load((const f32x4*)&x[(size_t)n1 * F + cl4]);
            f32x4 v2 = __builtin_nontemporal_load((const f32x4*)&x[(size_t)n2 * F + cl4]);
            f32x4 v3 = __builtin_nontemporal_load((const f32x4*)&x[(size_t)n3 * F + cl4]);
            f32x4 v4 = __builtin_nontemporal_load((const f32x4*)&x[(size_t)n4 * F + cl4]);
            f32x4 v5 = __builtin_nontemporal_load((const f32x4*)&x[(size_t)n5 * F + cl4]);
            f32x4 v6 = __builtin_nontemporal_load((const f32x4*)&x[(size_t)n6 * F + cl4]);
            f32x4 v7 = __builtin_nontemporal_load((const f32x4*)&x[(size_t)n7 * F + cl4]);
            m0 = vmax4(m0, v0);
            m1 = vmax4(m1, v1);
            m2 = vmax4(m2, v2);
            m3 = vmax4(m3, v3);
            m4 = vmax4(m4, v4);
            m5 = vmax4(m5, v5);
            m6 = vmax4(m6, v6);
            m7 = vmax4(m7, v7);
        }
    }
    m0 = vmax4(vmax4(vmax4(m0, m1), vmax4(m2, m3)),
               vmax4(vmax4(m4, m5), vmax4(m6, m7)));
    #pragma unroll
    for (int o = 16; o <= 32; o <<= 1) {
        m0.x = fmaxf(m0.x, __shfl_xor(m0.x, o));
        m0.y = fmaxf(m0.y, __shfl_xor(m0.y, o));
        m0.z = fmaxf(m0.z, __shfl_xor(m0.z, o));
        m0.w = fmaxf(m0.w, __shfl_xor(m0.w, o));
    }
    if (g == 0) {
        f32x4 r;
        if (end > beg) r = m0;
        else { r.x = r.y = r.z = r.w = 0.f; }
        *(f32x4*)&out_x[(size_t)s * F + cl4] = r;
    }
}

// ---- edge keys + coarse histogram ----
__global__ __launch_bounds__(PTHR) void k_ehist(const int* __restrict__ ei, int e,
                        const int* __restrict__ cl,
                        unsigned* __restrict__ keysA, unsigned* __restrict__ etable) {
    __shared__ unsigned hist[NBIN];
    int t = threadIdx.x, b = blockIdx.x;
    for (int j = t; j < NBIN; j += PTHR) hist[j] = 0u;
    __syncthreads();
    for (int i = b * PTHR + t; i < e; i += GPART * PTHR) {
        unsigned r = (unsigned)cl[ei[i]];
        unsigned c = (unsigned)cl[ei[e + i]];
        unsigned k = (r << 16) | c;
        keysA[i] = k;
        atomicAdd(&hist[k >> BSH], 1u);
    }
    __syncthreads();
    for (int j = t; j < NBIN; j += PTHR) etable[j * GPART + b] = hist[j];
}

// ---- coalesced coarse partition (A -> B); counts from SCANNED-TABLE DIFFS ----
__global__ __launch_bounds__(PTHR) void k_partition(const unsigned* __restrict__ keysA, int e,
                            const unsigned* __restrict__ etable,
                            unsigned* __restrict__ keysB) {
    __shared__ unsigned stage[8192];
    __shared__ unsigned h[NBIN], cur[NBIN], tbl_s[NBIN];
    int t = threadIdx.x, b = blockIdx.x;
    unsigned a = etable[t * GPART + b];            // boundary etable[ETBL] = e
    unsigned hv = etable[t * GPART + b + 1] - a;
    tbl_s[t] = a;
    h[t] = hv;
    __syncthreads();
    unsigned incl = block_incl_scan<PTHR>(hv, t);
    cur[t] = incl - hv;
    __syncthreads();
    for (int i = b * PTHR + t; i < e; i += GPART * PTHR) {
        unsigned k = keysA[i];
        unsigned p = atomicAdd(&cur[k >> BSH], 1u);
        stage[p] = k;
    }
    __syncthreads();
    int cnt = (int)cur[NBIN - 1];                  // block total after placement
    for (int j = t; j < cnt; j += PTHR) {
        unsigned k = stage[j];
        unsigned bin = k >> BSH;
        unsigned start = cur[bin] - h[bin];
        keysB[tbl_s[bin] + ((unsigned)j - start)] = k;
    }
}

// ---- 13-bit LDS counting sort per coarse bin + run-finish + FINAL edge outputs ----
__global__ __launch_bounds__(512) void k_subsort(const unsigned* __restrict__ src,
                         unsigned* __restrict__ scratch, const unsigned* __restrict__ table,
                         const float2* __restrict__ pos_pool,
                         float* __restrict__ out_erow, float* __restrict__ out_ecol,
                         float* __restrict__ out_valid, float2* __restrict__ out_attr,
                         float* __restrict__ pmax) {
    __shared__ unsigned hist[8192];     // slot(d) = (d&15)*512 + (d>>4)
    __shared__ unsigned stage[SCAP];
    __shared__ float shm[8];
    int b = blockIdx.x, t = threadIdx.x;
    int beg = (int)table[b * GPART];
    int end = (int)table[(b + 1) * GPART];   // b==NBIN-1 -> table[ETBL]==e
    int len = end - beg;
    if (len <= 0) { if (t == 0) pmax[b] = 0.f; return; }
    for (int j = t; j < 8192; j += 512) hist[j] = 0u;
    __syncthreads();
    for (int i = beg + t; i < end; i += 512) {
        unsigned d = (src[i] >> 10) & 8191u;
        atomicAdd(&hist[((d & 15u) << 9) | (d >> 4)], 1u);
    }
    __syncthreads();
    unsigned loc[16];
    unsigned s = 0;
    #pragma unroll
    for (int u = 0; u < 16; ++u) { loc[u] = s; s += hist[u * 512 + t]; }
    unsigned incl = block_incl_scan<512>(s, t);
    bool inlds = (len <= SCAP);
    unsigned base0 = (inlds ? 0u : (unsigned)beg) + incl - s;
    #pragma unroll
    for (int u = 0; u < 16; ++u) hist[u * 512 + t] = base0 + loc[u];
    __syncthreads();
    float am = 0.f;
    if (inlds) {
        for (int i = beg + t; i < end; i += 512) {
            unsigned k = src[i];
            unsigned d = (k >> 10) & 8191u;
            stage[atomicAdd(&hist[((d & 15u) << 9) | (d >> 4)], 1u)] = k;
        }
        __syncthreads();
        // run-finish: runs = equal top-22 bits (never cross bins); sort low 10 bits
        for (int j = t; j < len; j += 512) {
            unsigned hi = stage[j] >> 10;
            if (j > 0 && (stage[j - 1] >> 10) == hi) continue;
            int rend = j + 1;
            while (rend < len && (stage[rend] >> 10) == hi) ++rend;
            for (int a2 = j + 1; a2 < rend; ++a2) {
                unsigned v = stage[a2]; int c = a2 - 1;
                while (c >= j && stage[c] > v) { stage[c + 1] = stage[c]; --c; }
                stage[c + 1] = v;
            }
        }
        __syncthreads();
        for (int j = t; j < len; j += 512) {
            unsigned k = stage[j];
            bool first = (j == 0) || (stage[j - 1] != k);
            unsigned r = k >> 16, c = k & 0xFFFFu;
            bool valid = first && (r != c);
            float ax, ay;
            if (valid) {
                float2 pr = pos_pool[r], pcc = pos_pool[c];
                ax = pr.x - pcc.x; ay = pr.y - pcc.y;
                am = fmaxf(am, fmaxf(fabsf(ax), fabsf(ay)));
            } else {
                ax = __int_as_float(0x7FC00000); ay = 0.f;   // NaN sentinel
            }
            out_erow[beg + j]  = valid ? (float)r : 0.f;
            out_ecol[beg + j]  = valid ? (float)c : 0.f;
            out_valid[beg + j] = valid ? 1.f : 0.f;
            out_attr[beg + j]  = make_float2(ax, ay);
        }
    } else {
        // 27-sigma-unreachable fallback: scatter + run-finish in global scratch
        for (int i = beg + t; i < end; i += 512) {
            unsigned k = src[i];
            unsigned d = (k >> 10) & 8191u;
            scratch[atomicAdd(&hist[((d & 15u) << 9) | (d >> 4)], 1u)] = k;
        }
        __threadfence();
        __syncthreads();
        for (int j = beg + t; j < end; j += 512) {
            unsigned hi = scratch[j] >> 10;
            if (j > beg && (scratch[j - 1] >> 10) == hi) continue;
            int rend = j + 1;
            while (rend < end && (scratch[rend] >> 10) == hi) ++rend;
            for (int a2 = j + 1; a2 < rend; ++a2) {
                unsigned v = scratch[a2]; int c = a2 - 1;
                while (c >= j && scratch[c] > v) { scratch[c + 1] = scratch[c]; --c; }
                scratch[c + 1] = v;
            }
        }
        __threadfence();
        __syncthreads();
        for (int j = beg + t; j < end; j += 512) {
            unsigned k = scratch[j];
            bool first = (j == beg) || (scratch[j - 1] != k);
            unsigned r = k >> 16, c = k & 0xFFFFu;
            bool valid = first && (r != c);
            float ax, ay;
            if (valid) {
                float2 pr = pos_pool[r], pcc = pos_pool[c];
                ax = pr.x - pcc.x; ay = pr.y - pcc.y;
                am = fmaxf(am, fmaxf(fabsf(ax), fabsf(ay)));
            } else {
                ax = __int_as_float(0x7FC00000); ay = 0.f;
            }
            out_erow[j]  = valid ? (float)r : 0.f;
            out_ecol[j]  = valid ? (float)c : 0.f;
            out_valid[j] = valid ? 1.f : 0.f;
            out_attr[j]  = make_float2(ax, ay);
        }
    }
    am = wave_max(am);
    if ((t & 63) == 0) shm[t >> 6] = am;
    __syncthreads();
    if (t == 0) {
        float m = shm[0];
        #pragma unroll
        for (int i2 = 1; i2 < 8; ++i2) m = fmaxf(m, shm[i2]);
        pmax[b] = m;
    }
}

// ---- in-place rescale: attr = cart/(2*max) + 0.5 (NaN sentinel -> 0) ----
__global__ __launch_bounds__(256) void k_rescale(float2* __restrict__ out_attr, int e,
                                                 const float* __restrict__ pmax) {
    __shared__ float shm[4];
    int t = threadIdx.x;
    float m = fmaxf(pmax[t], pmax[t + 256]);
    m = wave_max(m);
    if ((t & 63) == 0) shm[t >> 6] = m;
    __syncthreads();
    float denom = 2.0f * fmaxf(fmaxf(shm[0], shm[1]), fmaxf(shm[2], shm[3]));
    int i = blockIdx.x * blockDim.x + t;
    if (i >= e) return;
    float2 a = out_attr[i];
    bool valid = (a.x == a.x);
    float ax = valid ? a.x / denom + 0.5f : 0.f;
    float ay = valid ? a.y / denom + 0.5f : 0.f;
    out_attr[i] = make_float2(ax, ay);
}

extern "C" void kernel_launch(void* const* d_in, const int* in_sizes, int n_in,
                              void* d_out, int out_size, void* d_ws, size_t ws_size,
                              hipStream_t stream) {
    const float* x    = (const float*)d_in[0];
    const float* pos  = (const float*)d_in[1];
    const int* batch  = (const int*)d_in[2];
    const int* ei     = (const int*)d_in[3];
    const int n = in_sizes[2];
    const int e = in_sizes[3] / 2;

    float* out      = (float*)d_out;
    float* out_x    = out;                                   // [SEG, F]
    float* out_pos  = out_x  + (size_t)SEG * F;              // [SEG, 2]
    float* out_erow = out_pos + (size_t)SEG * 2;             // [E]
    float* out_ecol = out_erow + e;                          // [E]
    float* out_attr = out_ecol + e;                          // [E, 2]
    float* out_val  = out_attr + (size_t)2 * e;              // [E]

    const int nb_e = (e + 255) / 256;

    char* w = (char*)d_ws;
    unsigned* hdr         = (unsigned*)w;                            // 2 u32 (pad 256)
    int*      cl          = (int*)(w + 256);                         // [n]
    int*      node_sorted = (int*)(w + 256 + (size_t)n * 4);         // [n]
    unsigned* node_off    = (unsigned*)(w + 256 + (size_t)n * 8);    // [SEG+1]
    unsigned* table       = node_off + SEG + 1;                      // [ETBL+1] (ntable alias)
    unsigned* keysA       = table + ETBL + 1;                        // [e] (alias: pc)
    unsigned* keysB       = keysA + e;                               // [e] (alias: pn)
    float2*   ppos        = (float2*)(keysB + e);                    // [n]
    unsigned* blksum      = (unsigned*)(ppos + n);                   // [256]
    float2*   pmin        = (float2*)(blksum + 256);                 // [MINB]
    float*    pmax        = (float*)(pmin + MINB);                   // [NBIN]
    unsigned* ntable      = table;                                   // lifetime-disjoint alias
    unsigned* pc          = keysA;
    unsigned* pn          = keysB;

    // node side
    k_min<<<MINB, 256, 0, stream>>>((const float2*)pos, n, pmin);
    k_minred<<<1, 256, 0, stream>>>(pmin, MINB, hdr);
    k_cluster<<<NGP, NTH, 0, stream>>>((const float2*)pos, batch, n, hdr, cl, ntable);
    k_scan1<<<NTBL / 1024, 1024, 0, stream>>>(ntable, ntable, blksum);
    k_scan_add<<<NTBL / 1024, 1024, 0, stream>>>(ntable, blksum, NTBL / 1024, NTBL, (unsigned)n);
    k_npart<<<NGP, NTH, 0, stream>>>(cl, (const float2*)pos, n, ntable, pc, pn, ppos);
    k_ngroup<<<NBIN, 256, 0, stream>>>(pc, pn, ppos, ntable, n, node_off, node_sorted,
                                       (float2*)out_pos);
    k_pool<<<SEG / 4, 256, 0, stream>>>(x, node_sorted, node_off, out_x);
    // edge side
    k_ehist<<<GPART, PTHR, 0, stream>>>(ei, e, cl, keysA, table);
    k_scan1<<<ETBL / 1024, 1024, 0, stream>>>(table, table, blksum);   // in-place safe
    k_scan_add<<<ETBL / 1024, 1024, 0, stream>>>(table, blksum, ETBL / 1024, ETBL, (unsigned)e);
    k_partition<<<GPART, PTHR, 0, stream>>>(keysA, e, table, keysB);
    k_subsort<<<NBIN, 512, 0, stream>>>(keysB, keysA, table, (const float2*)out_pos,
                                        out_erow, out_ecol, out_val, (float2*)out_attr, pmax);
    k_rescale<<<nb_e, 256, 0, stream>>>((float2*)out_attr, e, pmax);
}